// Round 19
// baseline (54.557 us; speedup 1.0000x reference)
//
#include <hip/hip_runtime.h>
#include <hip/hip_bf16.h>

typedef __attribute__((ext_vector_type(4))) float f32x4;
typedef __attribute__((ext_vector_type(8))) short short8;
typedef __attribute__((ext_vector_type(8))) unsigned short ushort8;
typedef __attribute__((ext_vector_type(4))) unsigned short ushort4v;

#define M_ROWS 16384
#define KDIM 512
#define UDIM 512
#define IN_STRIDE 1024
#define NKT 8             // K-tiles of 64

__device__ __forceinline__ unsigned short f2bf(float f) {
    union { float f; unsigned u; } v; v.f = f;
    unsigned r = v.u + 0x7FFFu + ((v.u >> 16) & 1u);  // RTNE
    return (unsigned short)(r >> 16);
}

__device__ __forceinline__ unsigned cvt2(float a, float b) {
    __hip_bfloat162 h = __float22bfloat162_rn(float2{a, b});
    union { __hip_bfloat162 h; unsigned u; } c; c.h = h; return c.u;
}

#define GLD16(g, l)                                                            \
    __builtin_amdgcn_global_load_lds(                                          \
        (const __attribute__((address_space(1))) void*)(g),                    \
        (__attribute__((address_space(3))) void*)(l), 16, 0, 0)

// ---------------------------------------------------------------------------
// weights pack: Wp[bx 4][kt 8][s 2048] x 16B. slot s: jj-row r=s>>3 (0..255),
// phys piece p=s&7, logical k-octet l = p ^ (r&7) (T2 swizzle baked).
// jj layout per 256-tile: wn=r>>6 (wave), gate=(r>>5)&1 (0=z,1=h), uoff=r&31;
// u = bx*128 + wn*32 + uoff. Content = w[kt*64 + l*8 .. +8][u] as bf16x8.
// Linear in s so gru_gemm's global_load_lds consumes it with LDS linear.
// ---------------------------------------------------------------------------
__global__ __launch_bounds__(256) void pack_w(
    const float* __restrict__ w_z,
    const float* __restrict__ w_h,
    unsigned short* __restrict__ Wp)
{
    int g  = blockIdx.x * 256 + threadIdx.x;   // [0, 65536)
    int s  = g & 2047;
    int kt = (g >> 11) & 7;
    int bx = g >> 14;
    int r  = s >> 3;
    int p  = s & 7;
    int l  = p ^ (r & 7);
    int k0 = kt * 64 + l * 8;
    int wn   = r >> 6;
    int gate = (r >> 5) & 1;
    int u    = bx * 128 + wn * 32 + (r & 31);
    const float* w = gate ? w_h : w_z;
    ushort8 v;
#pragma unroll
    for (int i = 0; i < 8; ++i)
        v[i] = f2bf(w[(size_t)(k0 + i) * UDIM + u]);
    *reinterpret_cast<ushort8*>(Wp + (size_t)g * 8) = v;
}

// ---------------------------------------------------------------------------
// 8-phase-template GEMM (T2+T3+T4+T5), fused A-conversion:
//  tile 128(M) x 256(jj), 8 waves (2Mx4N), BK=64, 8 K-tiles, ring-2 LDS.
//  Per K-tile: 4 quadrant phases {8 ds_read -> barrier -> lgkm(0) ->
//  setprio(1) -> 8 MFMA -> setprio(0) -> barrier}. Loads issued ph1/ph2
//  fly across 3 barriers; single vmcnt(0) + A cvt/ds_write at ph4 tail.
//  Both LDS tiles piece-XOR swizzled (p = l ^ (r&7), 128B rows).
// ---------------------------------------------------------------------------
__global__ __launch_bounds__(512, 2) void gru_gemm(
    const float* __restrict__ x,            // (16384,1024), cols [0,512) used
    const unsigned short* __restrict__ Wp,  // packed weights (1 MiB)
    const float* __restrict__ b_z,
    const float* __restrict__ b_h,
    float* __restrict__ out)
{
    __shared__ __align__(16) unsigned char smem[98304];
    unsigned short* shA = (unsigned short*)smem;            // 2 x 8192 u16
    unsigned short* shB = (unsigned short*)(smem + 32768);  // 2 x 16384 u16

    const int tid  = threadIdx.x;
    const int lane = tid & 63;
    const int wid  = tid >> 6;     // 0..7
    const int wm   = wid >> 2;     // 0..1  (M half)
    const int wn   = wid & 3;      // 0..3  (jj quarter)

    // XCD-aware bijective swizzle (512 = 8 XCD x 64): 4 bx-tiles of one
    // row-panel land adjacent on one XCD -> x panel L2-shared.
    const int d  = blockIdx.x;
    const int t  = (d >> 3) + (d & 7) * 64;
    const int by = t >> 2;          // 0..127
    const int bx = t & 3;           // 0..3
    const int brow = by * 128;
    const int u0t  = bx * 128;

    // ---- A staging geometry: 2 slots/thread; slot s: r=s>>3, p=s&7,
    //      content k-octet l = p ^ (r&7) ----
    const int sA0 = tid, sA1 = tid + 512;
    const int rA0 = sA0 >> 3, rA1 = sA1 >> 3;
    const int lA0 = (sA0 & 7) ^ (rA0 & 7);
    const int lA1 = (sA1 & 7) ^ (rA1 & 7);
    const float* gxA0 = x + (size_t)(brow + rA0) * IN_STRIDE + lA0 * 8;
    const float* gxA1 = x + (size_t)(brow + rA1) * IN_STRIDE + lA1 * 8;

    const unsigned short* bp = Wp + (size_t)bx * 8 * 2048 * 8;

    f32x4 acc[4][4];
#pragma unroll
    for (int m = 0; m < 4; ++m)
#pragma unroll
        for (int n = 0; n < 4; ++n)
            acc[m][n] = (f32x4){0.f, 0.f, 0.f, 0.f};

    // A in-flight regs (depth-1, named -> spill-proof)
    f32x4 as0lo, as0hi, as1lo, as1hi;

#define ISSUE_A(kt1)                                                           \
    {                                                                          \
        as0lo = *reinterpret_cast<const f32x4*>(gxA0 + (kt1) * 64);            \
        as0hi = *reinterpret_cast<const f32x4*>(gxA0 + (kt1) * 64 + 4);        \
        as1lo = *reinterpret_cast<const f32x4*>(gxA1 + (kt1) * 64);            \
        as1hi = *reinterpret_cast<const f32x4*>(gxA1 + (kt1) * 64 + 4);        \
    }

#define ISSUE_B2(kt1, q0_)                                                     \
    {                                                                          \
        GLD16(bp + ((size_t)(kt1) * 2048 + tid + (q0_) * 512) * 8,             \
              shB + ((kt1) & 1) * 16384 + (tid + (q0_) * 512) * 8);            \
        GLD16(bp + ((size_t)(kt1) * 2048 + tid + ((q0_) + 1) * 512) * 8,       \
              shB + ((kt1) & 1) * 16384 + (tid + ((q0_) + 1) * 512) * 8);      \
    }

#define CVT_WRITE_A(kt1)                                                       \
    {                                                                          \
        union { unsigned u[4]; ushort8 v; } c0, c1;                            \
        c0.u[0] = cvt2(as0lo[0], as0lo[1]); c0.u[1] = cvt2(as0lo[2], as0lo[3]);\
        c0.u[2] = cvt2(as0hi[0], as0hi[1]); c0.u[3] = cvt2(as0hi[2], as0hi[3]);\
        c1.u[0] = cvt2(as1lo[0], as1lo[1]); c1.u[1] = cvt2(as1lo[2], as1lo[3]);\
        c1.u[2] = cvt2(as1hi[0], as1hi[1]); c1.u[3] = cvt2(as1hi[2], as1hi[3]);\
        *reinterpret_cast<ushort8*>(&shA[((kt1) & 1) * 8192 + sA0 * 8]) = c0.v;\
        *reinterpret_cast<ushort8*>(&shA[((kt1) & 1) * 8192 + sA1 * 8]) = c1.v;\
    }

    // fragment read offsets (u16 units): row r, k-sub s32, lane k-quarter ks:
    // phys piece p = (s32*4+ks) ^ (r&7); off = (r*8+p)*8
    const int fr = lane & 15;
    const int ks = lane >> 4;
    int aoffs[4][2], boffs[4][2];
#pragma unroll
    for (int i = 0; i < 4; ++i)
#pragma unroll
        for (int s32 = 0; s32 < 2; ++s32) {
            int ra = wm * 64 + i * 16 + fr;
            aoffs[i][s32] = (ra * 8 + ((s32 * 4 + ks) ^ (ra & 7))) * 8;
            int rb = wn * 64 + i * 16 + fr;
            boffs[i][s32] = (rb * 8 + ((s32 * 4 + ks) ^ (rb & 7))) * 8;
        }

    // prologue: stage K-tile 0 (A regs + B LDS), land, write A(0), publish
    ISSUE_A(0);
    ISSUE_B2(0, 0);
    ISSUE_B2(0, 2);
    asm volatile("s_waitcnt vmcnt(0)" ::: "memory");
    CVT_WRITE_A(0);
    asm volatile("s_waitcnt lgkmcnt(0)" ::: "memory");
    asm volatile("s_barrier" ::: "memory");

#pragma unroll
    for (int kt = 0; kt < NKT; ++kt) {
        const int abase = (kt & 1) * 8192;
        const int bbase = (kt & 1) * 16384;
#pragma unroll
        for (int ph = 0; ph < 4; ++ph) {
            const int mh = ph >> 1, nh = ph & 1;
            // frag ds_reads for this quadrant
            short8 af[2][2], bf[2][2];
#pragma unroll
            for (int i2 = 0; i2 < 2; ++i2)
#pragma unroll
                for (int s32 = 0; s32 < 2; ++s32) {
                    af[i2][s32] = *reinterpret_cast<const short8*>(
                        &shA[abase + aoffs[mh * 2 + i2][s32]]);
                    bf[i2][s32] = *reinterpret_cast<const short8*>(
                        &shB[bbase + boffs[nh * 2 + i2][s32]]);
                }
            // stage issues for kt+1 (fly across the next 3 barriers)
            if (kt + 1 < NKT) {
                if (ph == 0) { ISSUE_A(kt + 1); ISSUE_B2(kt + 1, 0); }
                if (ph == 1) { ISSUE_B2(kt + 1, 2); }
            }
            asm volatile("s_barrier" ::: "memory");
            asm volatile("s_waitcnt lgkmcnt(0)" ::: "memory");
            __builtin_amdgcn_s_setprio(1);
#pragma unroll
            for (int i2 = 0; i2 < 2; ++i2)
#pragma unroll
                for (int j2 = 0; j2 < 2; ++j2)
#pragma unroll
                    for (int s32 = 0; s32 < 2; ++s32)
                        acc[mh * 2 + i2][nh * 2 + j2] =
                            __builtin_amdgcn_mfma_f32_16x16x32_bf16(
                                af[i2][s32], bf[j2][s32],
                                acc[mh * 2 + i2][nh * 2 + j2], 0, 0, 0);
            __builtin_amdgcn_s_setprio(0);
            if (ph == 3 && kt + 1 < NKT) {
                // iteration tail: land kt+1 (A regs + B LDS), write A, publish
                asm volatile("s_waitcnt vmcnt(0)" ::: "memory");
                CVT_WRITE_A(kt + 1);
                asm volatile("s_waitcnt lgkmcnt(0)" ::: "memory");
            }
            asm volatile("s_barrier" ::: "memory");
        }
    }

    __syncthreads();   // full fence before LDS reuse

    // ---- epilogue: s = sigmoid(z+bz)*tanh(h+bh) -> plane [128][132] ----
    float* plane = (float*)smem;   // 128*132*4 = 67584 B
    const int fq = ks;
#pragma unroll
    for (int p = 0; p < 2; ++p) {
        int ucol = wn * 32 + p * 16 + fr;          // 0..127 within tile
        float bz = b_z[u0t + ucol];
        float bh = b_h[u0t + ucol];
#pragma unroll
        for (int mi = 0; mi < 4; ++mi) {
            int row0 = wm * 64 + mi * 16 + fq * 4;
            f32x4 az = acc[mi][p];       // z-gate
            f32x4 ah = acc[mi][p + 2];   // h-candidate
#pragma unroll
            for (int j = 0; j < 4; ++j) {
                float zt = 1.f / (1.f + __expf(-(az[j] + bz)));
                float e  = __expf(2.f * (ah[j] + bh));
                float s  = zt * (1.f - 2.f / (e + 1.f));
                plane[(row0 + j) * 132 + ucol] = s;
            }
        }
    }
    __syncthreads();

    // ---- coalesced stores: 512B/row contiguous across 32 lanes ----
    float* fwd = out;
    float* seq = out + (size_t)M_ROWS * 1024;
    const f32x4 z4 = (f32x4){0.f, 0.f, 0.f, 0.f};
#pragma unroll
    for (int it = 0; it < 8; ++it) {
        int idx = it * 512 + tid;
        int row = idx >> 5;
        int c4  = (idx & 31) * 4;
        f32x4 v = *reinterpret_cast<const f32x4*>(&plane[row * 132 + c4]);
        size_t grow = (size_t)(brow + row);
        *reinterpret_cast<f32x4*>(&fwd[grow * 1024 + u0t + c4])       = v;
        *reinterpret_cast<f32x4*>(&fwd[grow * 1024 + 512 + u0t + c4]) = z4;
        *reinterpret_cast<f32x4*>(&seq[grow * 512 + u0t + c4])        = v;
    }
#undef ISSUE_A
#undef ISSUE_B2
#undef CVT_WRITE_A
}

// ---------------------------------------------------------------------------
// Legacy fallback (round-1 kernel, needs no workspace) if ws is too small
// ---------------------------------------------------------------------------
#define LDSS 40
__global__ __launch_bounds__(256) void gru_fused_legacy(
    const float* __restrict__ inp, const float* __restrict__ w_z,
    const float* __restrict__ b_z, const float* __restrict__ w_h,
    const float* __restrict__ b_h, float* __restrict__ out)
{
    __shared__ __align__(16) unsigned short Asl[2][128][LDSS];
    __shared__ __align__(16) unsigned short Bsl[2][128][LDSS];
    const int tid = threadIdx.x, lane = tid & 63, wid = tid >> 6;
    const int wm = wid >> 1, wn = wid & 1;
    const int u0 = blockIdx.x * 64, brow = blockIdx.y * 128;
    f32x4 acc[4][4];
#pragma unroll
    for (int m = 0; m < 4; ++m)
#pragma unroll
        for (int n = 0; n < 4; ++n) acc[m][n] = (f32x4){0.f,0.f,0.f,0.f};
    f32x4 rA[4], rB[4];
#define STAGE_LOAD(kt) { const int k0_=(kt)*32; \
    _Pragma("unroll") for (int it=0; it<4; ++it){ int idx=tid+256*it; int r=idx>>3,c=(idx&7)<<2; \
        rA[it]=*reinterpret_cast<const f32x4*>(inp+(size_t)(brow+r)*IN_STRIDE+k0_+c);} \
    _Pragma("unroll") for (int it=0; it<4; ++it){ int idx=tid+256*it; int jj=idx&127; int k4=(idx>>7)<<2; \
        const float* w_=((jj>>5)&1)?w_h:w_z; int u_=u0+((jj>>6)<<5)+(jj&31); \
        const float* p_=w_+(size_t)(k0_+k4)*UDIM+u_; \
        rB[it][0]=p_[0]; rB[it][1]=p_[UDIM]; rB[it][2]=p_[2*UDIM]; rB[it][3]=p_[3*UDIM];} }
#define STAGE_WRITE(bufi) { \
    _Pragma("unroll") for (int it=0; it<4; ++it){ int idx=tid+256*it; int r=idx>>3,c=(idx&7)<<2; ushort4v v; \
        v[0]=f2bf(rA[it][0]); v[1]=f2bf(rA[it][1]); v[2]=f2bf(rA[it][2]); v[3]=f2bf(rA[it][3]); \
        *reinterpret_cast<ushort4v*>(&Asl[bufi][r][c])=v;} \
    _Pragma("unroll") for (int it=0; it<4; ++it){ int idx=tid+256*it; int jj=idx&127; int k4=(idx>>7)<<2; ushort4v v; \
        v[0]=f2bf(rB[it][0]); v[1]=f2bf(rB[it][1]); v[2]=f2bf(rB[it][2]); v[3]=f2bf(rB[it][3]); \
        *reinterpret_cast<ushort4v*>(&Bsl[bufi][jj][k4])=v;} }
    STAGE_LOAD(0); STAGE_WRITE(0);
    const int fr = lane & 15, koff = (lane >> 4) << 3;
    for (int kt = 0; kt < 16; ++kt) {
        if (kt + 1 < 16) STAGE_LOAD(kt + 1);
        __syncthreads();
        const int buf = kt & 1;
        short8 af[4], bfr[4];
#pragma unroll
        for (int m = 0; m < 4; ++m) af[m] = *reinterpret_cast<const short8*>(&Asl[buf][wm*64+m*16+fr][koff]);
#pragma unroll
        for (int n = 0; n < 4; ++n) bfr[n] = *reinterpret_cast<const short8*>(&Bsl[buf][wn*64+n*16+fr][koff]);
#pragma unroll
        for (int m = 0; m < 4; ++m)
#pragma unroll
            for (int n = 0; n < 4; ++n)
                acc[m][n] = __builtin_amdgcn_mfma_f32_16x16x32_bf16(af[m], bfr[n], acc[m][n], 0, 0, 0);
        if (kt + 1 < 16) STAGE_WRITE((kt + 1) & 1);
    }
    float* fwd = out; float* seq = out + (size_t)M_ROWS * 1024;
    const int fq = lane >> 4;
#pragma unroll
    for (int p = 0; p < 2; ++p) {
        int u = u0 + wn * 32 + p * 16 + fr;
        float bz = b_z[u], bh = b_h[u];
#pragma unroll
        for (int m = 0; m < 4; ++m) {
            int row0 = brow + wm * 64 + m * 16 + fq * 4;
            f32x4 az = acc[m][p], ah = acc[m][p + 2];
#pragma unroll
            for (int j = 0; j < 4; ++j) {
                float zt = 1.f / (1.f + __expf(-(az[j] + bz)));
                float e  = __expf(2.f * (ah[j] + bh));
                float s  = zt * (1.f - 2.f / (e + 1.f));
                size_t rr = (size_t)(row0 + j);
                fwd[rr * 1024 + u] = s;
                fwd[rr * 1024 + 512 + u] = 0.f;
                seq[rr * 512 + u] = s;
            }
        }
    }
}

extern "C" void kernel_launch(void* const* d_in, const int* in_sizes, int n_in,
                              void* d_out, int out_size, void* d_ws, size_t ws_size,
                              hipStream_t stream) {
    const float* inp = (const float*)d_in[0];
    const float* w_z = (const float*)d_in[2];
    const float* b_z = (const float*)d_in[4];
    const float* w_h = (const float*)d_in[8];
    const float* b_h = (const float*)d_in[10];
    float* out = (float*)d_out;

    const size_t needW = (size_t)4 * 8 * 2048 * 16;   // 1 MiB packed weights
    if (ws_size >= needW) {
        unsigned short* Wp = (unsigned short*)d_ws;
        hipLaunchKernelGGL(pack_w, dim3(256), dim3(256), 0, stream, w_z, w_h, Wp);
        hipLaunchKernelGGL(gru_gemm, dim3(512), dim3(512), 0, stream,
                           inp, Wp, b_z, b_h, out);
    } else {
        hipLaunchKernelGGL(gru_fused_legacy, dim3(8, 128), dim3(256), 0, stream,
                           inp, w_z, b_z, w_h, b_h, out);
    }
}